// Round 18
// baseline (218.045 us; speedup 1.0000x reference)
//
#include <hip/hip_runtime.h>

// Strip-persistent pipelined fused 3x3 VALID conv (bf16 MFMA implicit GEMM).
// x:(16,2048,2048) fp32, k:(16,16,3,3) fp32 -> out:(16,2046,2046) fp32
// Each block owns a strip of 8 w-tiles at one h-band. Double-buffered bf16
// LDS regions (2 x 39168B). Per tile: ISSUE(t+1) [8 asm global_load_dwordx4,
// pinned before compute] -> COMPUTE(t) -> vmcnt(0) -> PACK(t+1) -> barrier.
// HBM reads for t+1 overlap compute+stores of t (T14 async-STAGE).
// Compute contract (verified R8..R17): 5x mfma_16x16x32_bf16 per 16x16
// sub-tile, XOR-swizzled [pos][ci] LDS layout.

#define HIN   2048
#define WIN   2048
#define HOUT  2046
#define WOUT  2046
#define PLANE_IN  (HIN * WIN)
#define PLANE_OUT (HOUT * WOUT)
#define TR 34
#define TC 36
#define NQTASK (TR * 9 * 2)            // 612 tasks per tile
#define BUFB (TR * TC * 32)            // 39168 bytes per bf16 buffer
#define WF_U32 (5 * 64 * 4)

typedef __attribute__((ext_vector_type(8))) short bf16x8;
typedef __attribute__((ext_vector_type(4))) float f32x4;
typedef __attribute__((ext_vector_type(4))) unsigned u32x4;
typedef f32x4 __attribute__((aligned(4))) f32x4_u;

static __device__ __forceinline__ short f2bf(float f) {
    unsigned u = __float_as_uint(f);
    return (short)((u + 0x7FFFu + ((u >> 16) & 1u)) >> 16);   // RNE
}
static __device__ __forceinline__ unsigned pk2(float lo, float hi) {
    unsigned a = __float_as_uint(lo);
    unsigned b = __float_as_uint(hi);
    a = (a + 0x7FFFu + ((a >> 16) & 1u)) >> 16;
    b = (b + 0x7FFFu + ((b >> 16) & 1u)) & 0xFFFF0000u;
    return a | b;
}

// ---------------- setup: per-lane MFMA weight fragments ----------------------
__global__ __launch_bounds__(64)
void wf_setup(const float* __restrict__ k, unsigned* __restrict__ wfbuf) {
    int lane = threadIdx.x;
    int m = lane & 15, g = lane >> 4;
    #pragma unroll
    for (int i = 0; i < 5; ++i) {
        u32x4 q;
        #pragma unroll
        for (int jj = 0; jj < 4; ++jj) {
            unsigned r = 0;
            #pragma unroll
            for (int e = 0; e < 2; ++e) {
                int kk  = 32 * i + 8 * g + 2 * jj + e;
                int tap = kk >> 4;
                int ci  = kk & 15;
                unsigned v = 0;
                if (tap < 9) v = (unsigned short)f2bf(k[(m * 16 + ci) * 9 + tap]);
                r |= v << (16 * e);
            }
            q[jj] = r;
        }
        *(u32x4*)(wfbuf + (i * 64 + lane) * 4) = q;
    }
}

#define GLOADX4(DST, ADDR) \
    asm volatile("global_load_dwordx4 %0, %1, off" : "=&v"(DST) : "v"(ADDR))

// ---------------- primary: strip-pipelined fused conv ------------------------
__global__ __launch_bounds__(1024, 2)
void conv3x3_pipe(const float* __restrict__ x,
                  const unsigned* __restrict__ wfbuf,
                  float* __restrict__ out) {
    extern __shared__ unsigned lds[];   // 2 x 39168 B

    const int tid  = threadIdx.x;
    const int lane = tid & 63;
    const int wv   = tid >> 6;              // 0..15
    const int m    = lane & 15;
    const int g    = lane >> 4;

    int bid   = blockIdx.x;                    // 512 blocks = 64 h x 8 strips
    int swz   = (bid & 7) * 64 + (bid >> 3);   // XCD-chunked (512 % 8 == 0)
    int htile = swz >> 3;
    int strip = swz & 7;
    int h0 = htile * 32; if (h0 > HOUT - 32) h0 = HOUT - 32;   // 2014
    const int wbase = strip * 256;

    // ---- per-thread stage-task constants ----
    const bool has = (tid < NQTASK);
    int q = 0, cih = 0, row = 0, c = 0, abase = 0;
    const float* gpr = x;
    if (has) {
        q   = tid % 9;
        int r2 = tid / 9;
        cih = r2 & 1;
        row = r2 >> 1;
        c   = 4 * q;
        gpr = x + (size_t)(cih * 8) * PLANE_IN + (size_t)(h0 + row) * WIN;
        abase = ((row * TC + c) * 32 + cih * 16) ^ ((c & 4) << 2);
    }

    // ---- per-lane A-fragment LDS byte offsets (verified contract) ----
    int off[5];
    #pragma unroll
    for (int i = 0; i < 5; ++i) {
        int tap = 2 * i + (g >> 1);
        if (tap > 8) tap = 8;                   // dead K (weights are 0)
        int kh = tap / 3;
        int kw = tap - kh * 3;
        int col = m + kw;
        int o = (kh * TC + col) * 32 + (g & 1) * 16;
        off[i] = o ^ ((col & 4) << 2);
    }

    f32x4 f0, f1, f2, f3, f4, f5, f6, f7;       // in-flight payload (held)

#define ISSUE(W0) do {                                                        \
        if (has) {                                                            \
            int w = (W0) + c; if (w > WIN - 4) w = WIN - 4;                   \
            const float* gp = gpr + w;                                        \
            GLOADX4(f0, gp + 0 * (size_t)PLANE_IN);                           \
            GLOADX4(f1, gp + 1 * (size_t)PLANE_IN);                           \
            GLOADX4(f2, gp + 2 * (size_t)PLANE_IN);                           \
            GLOADX4(f3, gp + 3 * (size_t)PLANE_IN);                           \
            GLOADX4(f4, gp + 4 * (size_t)PLANE_IN);                           \
            GLOADX4(f5, gp + 5 * (size_t)PLANE_IN);                           \
            GLOADX4(f6, gp + 6 * (size_t)PLANE_IN);                           \
            GLOADX4(f7, gp + 7 * (size_t)PLANE_IN);                           \
        }                                                                     \
        __builtin_amdgcn_sched_barrier(0);                                    \
    } while (0)

#define PACK(BUFOFF) do {                                                     \
        if (has) {                                                            \
            char* dst = (char*)lds + (BUFOFF) + abase;                        \
            u32x4 ch;                                                         \
            ch[0] = pk2(f0[0], f1[0]); ch[1] = pk2(f2[0], f3[0]);             \
            ch[2] = pk2(f4[0], f5[0]); ch[3] = pk2(f6[0], f7[0]);             \
            *(u32x4*)(dst)      = ch;                                         \
            ch[0] = pk2(f0[1], f1[1]); ch[1] = pk2(f2[1], f3[1]);             \
            ch[2] = pk2(f4[1], f5[1]); ch[3] = pk2(f6[1], f7[1]);             \
            *(u32x4*)(dst + 32) = ch;                                         \
            ch[0] = pk2(f0[2], f1[2]); ch[1] = pk2(f2[2], f3[2]);             \
            ch[2] = pk2(f4[2], f5[2]); ch[3] = pk2(f6[2], f7[2]);             \
            *(u32x4*)(dst + 64) = ch;                                         \
            ch[0] = pk2(f0[3], f1[3]); ch[1] = pk2(f2[3], f3[3]);             \
            ch[2] = pk2(f4[3], f5[3]); ch[3] = pk2(f6[3], f7[3]);             \
            *(u32x4*)(dst + 96) = ch;                                         \
        }                                                                     \
    } while (0)

#define COMPUTE(BUFOFF, W0) do {                                              \
        const char* ldsb = (const char*)lds + (BUFOFF);                       \
        bf16x8 wf[5];                                                         \
        _Pragma("unroll")                                                     \
        for (int i = 0; i < 5; ++i)                                           \
            wf[i] = *(const bf16x8*)(wfbuf + (i * 64 + lane) * 4);            \
        _Pragma("unroll")                                                     \
        for (int hl2 = 0; hl2 < 2; ++hl2) {                                   \
            int hl = wv * 2 + hl2;                                            \
            int h  = h0 + hl;                                                 \
            _Pragma("unroll")                                                 \
            for (int nh = 0; nh < 2; ++nh) {                                  \
                int wl = nh * 16;                                             \
                int tb = (hl * TC + wl) * 32;                                 \
                f32x4 acc = {0.f, 0.f, 0.f, 0.f};                             \
                _Pragma("unroll")                                             \
                for (int i = 0; i < 5; ++i) {                                 \
                    bf16x8 a = *(const bf16x8*)(ldsb + (tb + off[i]));        \
                    acc = __builtin_amdgcn_mfma_f32_16x16x32_bf16(            \
                              a, wf[i], acc, 0, 0, 0);                        \
                }                                                             \
                int w = (W0) + wl + g * 4;                                    \
                float* op = out + m * (size_t)PLANE_OUT                       \
                                + (size_t)h * WOUT + w;                       \
                if (w + 3 < WOUT) {                                           \
                    *(f32x4_u*)op = acc;                                      \
                } else {                                                      \
                    _Pragma("unroll")                                         \
                    for (int r = 0; r < 4; ++r)                               \
                        if (w + r < WOUT) op[r] = acc[r];                     \
                }                                                             \
            }                                                                 \
        }                                                                     \
    } while (0)

    // ---- prologue: stage tile 0 ----
    ISSUE(wbase);
    asm volatile("s_waitcnt vmcnt(0)" ::: "memory");
    __builtin_amdgcn_sched_barrier(0);
    PACK(0);
    __syncthreads();

    // ---- pipelined strip loop ----
    #pragma unroll 2
    for (int t = 0; t < 8; ++t) {
        const int buf  = (t & 1) * BUFB;
        const int nbuf = ((t + 1) & 1) * BUFB;
        if (t < 7) ISSUE(wbase + (t + 1) * 32);     // reads overlap compute
        COMPUTE(buf, wbase + t * 32);
        asm volatile("s_waitcnt vmcnt(0)" ::: "memory");
        __builtin_amdgcn_sched_barrier(0);
        if (t < 7) PACK(nbuf);
        __syncthreads();
    }
#undef ISSUE
#undef PACK
#undef COMPUTE
}

// ---------------- fallback A: R16 champion (149.2us total) -------------------
__global__ __launch_bounds__(1024, 2)
void conv3x3_fused1k(const float* __restrict__ x,
                     const unsigned* __restrict__ wfbuf,
                     float* __restrict__ out) {
    __shared__ unsigned lds[TR * TC * 8];

    const int tid  = threadIdx.x;
    const int lane = tid & 63;
    const int wv   = tid >> 6;
    const int m    = lane & 15;
    const int g    = lane >> 4;

    int bid = blockIdx.x;
    int swz = (bid & 7) * 512 + (bid >> 3);
    int h0 = (swz >> 6) * 32; if (h0 > HOUT - 32) h0 = HOUT - 32;
    int w0 = (swz & 63) * 32;

    if (tid < NQTASK) {
        int t   = tid;
        int q   = t % 9;
        int r2  = t / 9;
        int cih = r2 & 1;
        int row = r2 >> 1;
        int c   = 4 * q;
        int w   = w0 + c; if (w > WIN - 4) w = WIN - 4;
        const float* gp = x + (size_t)(cih * 8) * PLANE_IN
                            + (size_t)(h0 + row) * WIN + w;
        f32x4 f0 = *(const f32x4*)(gp + 0 * (size_t)PLANE_IN);
        f32x4 f1 = *(const f32x4*)(gp + 1 * (size_t)PLANE_IN);
        f32x4 f2 = *(const f32x4*)(gp + 2 * (size_t)PLANE_IN);
        f32x4 f3 = *(const f32x4*)(gp + 3 * (size_t)PLANE_IN);
        f32x4 f4 = *(const f32x4*)(gp + 4 * (size_t)PLANE_IN);
        f32x4 f5 = *(const f32x4*)(gp + 5 * (size_t)PLANE_IN);
        f32x4 f6 = *(const f32x4*)(gp + 6 * (size_t)PLANE_IN);
        f32x4 f7 = *(const f32x4*)(gp + 7 * (size_t)PLANE_IN);
        int a = ((row * TC + c) * 32 + cih * 16) ^ ((c & 4) << 2);
        u32x4 ch;
        ch[0] = pk2(f0[0], f1[0]); ch[1] = pk2(f2[0], f3[0]);
        ch[2] = pk2(f4[0], f5[0]); ch[3] = pk2(f6[0], f7[0]);
        *(u32x4*)((char*)lds + a)      = ch;
        ch[0] = pk2(f0[1], f1[1]); ch[1] = pk2(f2[1], f3[1]);
        ch[2] = pk2(f4[1], f5[1]); ch[3] = pk2(f6[1], f7[1]);
        *(u32x4*)((char*)lds + a + 32) = ch;
        ch[0] = pk2(f0[2], f1[2]); ch[1] = pk2(f2[2], f3[2]);
        ch[2] = pk2(f4[2], f5[2]); ch[3] = pk2(f6[2], f7[2]);
        *(u32x4*)((char*)lds + a + 64) = ch;
        ch[0] = pk2(f0[3], f1[3]); ch[1] = pk2(f2[3], f3[3]);
        ch[2] = pk2(f4[3], f5[3]); ch[3] = pk2(f6[3], f7[3]);
        *(u32x4*)((char*)lds + a + 96) = ch;
    }

    bf16x8 wf[5];
    #pragma unroll
    for (int i = 0; i < 5; ++i)
        wf[i] = *(const bf16x8*)(wfbuf + (i * 64 + lane) * 4);

    int off[5];
    #pragma unroll
    for (int i = 0; i < 5; ++i) {
        int tap = 2 * i + (g >> 1);
        if (tap > 8) tap = 8;
        int kh = tap / 3;
        int kw = tap - kh * 3;
        int col = m + kw;
        int o = (kh * TC + col) * 32 + (g & 1) * 16;
        off[i] = o ^ ((col & 4) << 2);
    }

    __syncthreads();

    const char* ldsb = (const char*)lds;

    #pragma unroll
    for (int hl2 = 0; hl2 < 2; ++hl2) {
        int hl = wv * 2 + hl2;
        int h  = h0 + hl;
        #pragma unroll
        for (int nh = 0; nh < 2; ++nh) {
            int wl = nh * 16;
            int tb = (hl * TC + wl) * 32;
            f32x4 acc = {0.f, 0.f, 0.f, 0.f};
            #pragma unroll
            for (int i = 0; i < 5; ++i) {
                bf16x8 a = *(const bf16x8*)(ldsb + (tb + off[i]));
                acc = __builtin_amdgcn_mfma_f32_16x16x32_bf16(a, wf[i], acc, 0, 0, 0);
            }
            int w = w0 + wl + g * 4;
            float* op = out + m * (size_t)PLANE_OUT + (size_t)h * WOUT + w;
            if (w + 3 < WOUT) {
                *(f32x4_u*)op = acc;
            } else {
                #pragma unroll
                for (int r = 0; r < 4; ++r)
                    if (w + r < WOUT) op[r] = acc[r];
            }
        }
    }
}

// ---------------- fallback B (no workspace): fp32-staged single pass ---------
__global__ __launch_bounds__(256, 4)
void conv3x3_mfma(const float* __restrict__ x,
                  const float* __restrict__ k,
                  float* __restrict__ out) {
    __shared__ short lds2[TR * 34 * 16];
    const int tid  = threadIdx.x;
    const int lane = tid & 63;
    const int wv   = tid >> 6;
    const int m    = lane & 15;
    const int g    = lane >> 4;
    int bid = blockIdx.x;
    int swz = (bid & 7) * 512 + (bid >> 3);
    int h0 = (swz >> 6) * 32;
    int w0 = (swz & 63) * 32;
    for (int p = tid; p < TR * 34; p += 256) {
        int r = p / 34, c = p - r * 34;
        int hh = h0 + r; if (hh > HIN - 1) hh = HIN - 1;
        int ww = w0 + c; if (ww > WIN - 1) ww = WIN - 1;
        const float* gp = x + hh * WIN + ww;
        short t[16];
        #pragma unroll
        for (int ci = 0; ci < 16; ++ci) t[ci] = f2bf(gp[ci * PLANE_IN]);
        bf16x8 lo, hi;
        #pragma unroll
        for (int j = 0; j < 8; ++j) { lo[j] = t[j]; hi[j] = t[8 + j]; }
        int sw = (c >> 2) & 1;
        bf16x8* dst = (bf16x8*)&lds2[p * 16];
        dst[sw] = lo; dst[1 - sw] = hi;
    }
    bf16x8 wf[5];
    #pragma unroll
    for (int i = 0; i < 5; ++i)
        #pragma unroll
        for (int j = 0; j < 8; ++j) {
            int kk = 32 * i + 8 * g + j;
            int tap = kk >> 4, ci = kk & 15;
            short v = 0;
            if (tap < 9) v = f2bf(k[(m * 16 + ci) * 9 + tap]);
            wf[i][j] = v;
        }
    int off[5];
    #pragma unroll
    for (int i = 0; i < 5; ++i) {
        int tap = 2 * i + (g >> 1);
        if (tap > 8) tap = 8;
        int kh = tap / 3, kw = tap - kh * 3;
        int col = m + kw;
        int o = (kh * 34 + col) * 32 + (g & 1) * 16;
        off[i] = o ^ ((col & 4) << 2);
    }
    __syncthreads();
    const char* ldsb = (const char*)lds2;
    const int coBase = g * 4;
    for (int hl8 = 0; hl8 < 8; ++hl8) {
        int hl = wv * 8 + hl8;
        int h = h0 + hl;
        bool hok = (h < HOUT);
        #pragma unroll
        for (int nh = 0; nh < 2; ++nh) {
            int wl = nh * 16;
            int tb = (hl * 34 + wl) * 32;
            f32x4 acc = {0.f, 0.f, 0.f, 0.f};
            #pragma unroll
            for (int i = 0; i < 5; ++i) {
                bf16x8 b = *(const bf16x8*)(ldsb + (tb + off[i]));
                acc = __builtin_amdgcn_mfma_f32_16x16x32_bf16(wf[i], b, acc, 0, 0, 0);
            }
            int w = w0 + wl + m;
            if (hok && w < WOUT) {
                float* op = out + h * WOUT + w;
                #pragma unroll
                for (int r = 0; r < 4; ++r)
                    op[(coBase + r) * PLANE_OUT] = acc[r];
            }
        }
    }
}

extern "C" void kernel_launch(void* const* d_in, const int* in_sizes, int n_in,
                              void* d_out, int out_size, void* d_ws, size_t ws_size,
                              hipStream_t stream) {
    const float* x = (const float*)d_in[0];
    const float* k = (const float*)d_in[1];
    float* out = (float*)d_out;
    if (ws_size >= WF_U32 * 4) {
        unsigned* wfbuf = (unsigned*)d_ws;
        wf_setup<<<dim3(1), dim3(64), 0, stream>>>(k, wfbuf);
        hipError_t e = hipFuncSetAttribute(
            reinterpret_cast<const void*>(conv3x3_pipe),
            hipFuncAttributeMaxDynamicSharedMemorySize, 2 * BUFB);
        if (e == hipSuccess) {
            conv3x3_pipe<<<dim3(512), dim3(1024), 2 * BUFB, stream>>>(x, wfbuf, out);
        } else {
            conv3x3_fused1k<<<dim3(4096), dim3(1024), 0, stream>>>(x, wfbuf, out);
        }
    } else {
        conv3x3_mfma<<<dim3(4096), dim3(256), 0, stream>>>(x, k, out);
    }
}

// Round 19
// 149.886 us; speedup vs baseline: 1.4547x; 1.4547x over previous
//
#include <hip/hip_runtime.h>

// Fused single-pass 3x3 VALID conv via bf16 MFMA implicit GEMM.
// x:(16,2048,2048) fp32, k:(16,16,3,3) fp32 -> out:(16,2046,2046) fp32
// 1024-thread blocks: each thread does AT MOST ONE stage task (8 plane-
// strided f32x4 loads -> 16 pk2 -> 4x ds_write_b128, XOR-swizzled), so the
// staging critical path is a single HBM latency; 39KB LDS x 2 blocks/CU.
// Compute: 5x mfma_16x16x32_bf16 per 16x16 sub-tile (verified contract,
// 2 rows per wave). Weight fragments precomputed once into d_ws.
// SESSION CHAMPION: 149.2us total (R16).

#define HIN   2048
#define WIN   2048
#define HOUT  2046
#define WOUT  2046
#define PLANE_IN  (HIN * WIN)
#define PLANE_OUT (HOUT * WOUT)
#define TR 34
#define TC 36                          // padded staging stride (cols)
#define NQTASK (TR * 9 * 2)            // 612: 34 rows x 9 w-quads x 2 ci-halves
#define WF_U32 (5 * 64 * 4)            // weight-frag buffer (5 KiB)

typedef __attribute__((ext_vector_type(8))) short bf16x8;
typedef __attribute__((ext_vector_type(4))) float f32x4;
typedef __attribute__((ext_vector_type(4))) unsigned u32x4;
typedef f32x4 __attribute__((aligned(4))) f32x4_u;

static __device__ __forceinline__ short f2bf(float f) {
    unsigned u = __float_as_uint(f);
    return (short)((u + 0x7FFFu + ((u >> 16) & 1u)) >> 16);   // RNE
}
static __device__ __forceinline__ unsigned pk2(float lo, float hi) {
    unsigned a = __float_as_uint(lo);
    unsigned b = __float_as_uint(hi);
    a = (a + 0x7FFFu + ((a >> 16) & 1u)) >> 16;
    b = (b + 0x7FFFu + ((b >> 16) & 1u)) & 0xFFFF0000u;
    return a | b;
}

// ---------------- setup: per-lane MFMA weight fragments ----------------------
__global__ __launch_bounds__(64)
void wf_setup(const float* __restrict__ k, unsigned* __restrict__ wfbuf) {
    int lane = threadIdx.x;
    int m = lane & 15, g = lane >> 4;
    #pragma unroll
    for (int i = 0; i < 5; ++i) {
        u32x4 q;
        #pragma unroll
        for (int jj = 0; jj < 4; ++jj) {
            unsigned r = 0;
            #pragma unroll
            for (int e = 0; e < 2; ++e) {
                int kk  = 32 * i + 8 * g + 2 * jj + e;
                int tap = kk >> 4;
                int ci  = kk & 15;
                unsigned v = 0;
                if (tap < 9) v = (unsigned short)f2bf(k[(m * 16 + ci) * 9 + tap]);
                r |= v << (16 * e);
            }
            q[jj] = r;
        }
        *(u32x4*)(wfbuf + (i * 64 + lane) * 4) = q;
    }
}

// ---------------- stage task body (shared by both fused kernels) -------------
#define STAGE_TASK_BODY(T, LDSPTR, W0, H0)                                    \
    do {                                                                      \
        int t   = (T);                                                        \
        int q   = t % 9;                                                      \
        int r2  = t / 9;                                                      \
        int cih = r2 & 1;                                                     \
        int row = r2 >> 1;                                                    \
        int c   = 4 * q;                                                      \
        int w   = (W0) + c; if (w > WIN - 4) w = WIN - 4;                     \
        const float* gp = x + (size_t)(cih * 8) * PLANE_IN                    \
                            + (size_t)((H0) + row) * WIN + w;                 \
        f32x4 f0 = *(const f32x4*)(gp + 0 * (size_t)PLANE_IN);                \
        f32x4 f1 = *(const f32x4*)(gp + 1 * (size_t)PLANE_IN);                \
        f32x4 f2 = *(const f32x4*)(gp + 2 * (size_t)PLANE_IN);                \
        f32x4 f3 = *(const f32x4*)(gp + 3 * (size_t)PLANE_IN);                \
        f32x4 f4 = *(const f32x4*)(gp + 4 * (size_t)PLANE_IN);                \
        f32x4 f5 = *(const f32x4*)(gp + 5 * (size_t)PLANE_IN);                \
        f32x4 f6 = *(const f32x4*)(gp + 6 * (size_t)PLANE_IN);                \
        f32x4 f7 = *(const f32x4*)(gp + 7 * (size_t)PLANE_IN);                \
        int a = ((row * TC + c) * 32 + cih * 16) ^ ((c & 4) << 2);            \
        u32x4 ch;                                                             \
        ch[0] = pk2(f0[0], f1[0]); ch[1] = pk2(f2[0], f3[0]);                 \
        ch[2] = pk2(f4[0], f5[0]); ch[3] = pk2(f6[0], f7[0]);                 \
        *(u32x4*)((char*)(LDSPTR) + a)      = ch;                             \
        ch[0] = pk2(f0[1], f1[1]); ch[1] = pk2(f2[1], f3[1]);                 \
        ch[2] = pk2(f4[1], f5[1]); ch[3] = pk2(f6[1], f7[1]);                 \
        *(u32x4*)((char*)(LDSPTR) + a + 32) = ch;                             \
        ch[0] = pk2(f0[2], f1[2]); ch[1] = pk2(f2[2], f3[2]);                 \
        ch[2] = pk2(f4[2], f5[2]); ch[3] = pk2(f6[2], f7[2]);                 \
        *(u32x4*)((char*)(LDSPTR) + a + 64) = ch;                             \
        ch[0] = pk2(f0[3], f1[3]); ch[1] = pk2(f2[3], f3[3]);                 \
        ch[2] = pk2(f4[3], f5[3]); ch[3] = pk2(f6[3], f7[3]);                 \
        *(u32x4*)((char*)(LDSPTR) + a + 96) = ch;                             \
    } while (0)

// ---------------- primary: 1024-thread fused conv ----------------
__global__ __launch_bounds__(1024, 2)
void conv3x3_fused1k(const float* __restrict__ x,
                     const unsigned* __restrict__ wfbuf,
                     float* __restrict__ out) {
    __shared__ unsigned lds[TR * TC * 8];   // 39168 B

    const int tid  = threadIdx.x;
    const int lane = tid & 63;
    const int wv   = tid >> 6;              // 0..15
    const int m    = lane & 15;
    const int g    = lane >> 4;

    int bid = blockIdx.x;                      // 4096 blocks (64 x 64 tiles)
    int swz = (bid & 7) * 512 + (bid >> 3);    // XCD-chunked (4096 % 8 == 0)
    int h0 = (swz >> 6) * 32; if (h0 > HOUT - 32) h0 = HOUT - 32;  // 2014
    int w0 = (swz & 63) * 32;

    // ---- stage: each thread does at most ONE task (single latency exposure)
    if (tid < NQTASK) STAGE_TASK_BODY(tid, lds, w0, h0);

    // ---- weight fragments: 5 coalesced 16B loads (L2-hot) ----
    bf16x8 wf[5];
    #pragma unroll
    for (int i = 0; i < 5; ++i)
        wf[i] = *(const bf16x8*)(wfbuf + (i * 64 + lane) * 4);

    // ---- per-lane A-fragment LDS byte offsets ----
    int off[5];
    #pragma unroll
    for (int i = 0; i < 5; ++i) {
        int tap = 2 * i + (g >> 1);
        if (tap > 8) tap = 8;                   // dead K (weights are 0)
        int kh = tap / 3;
        int kw = tap - kh * 3;
        int col = m + kw;
        int o = (kh * TC + col) * 32 + (g & 1) * 16;
        off[i] = o ^ ((col & 4) << 2);          // matches staging swizzle
    }

    __syncthreads();

    const char* ldsb = (const char*)lds;

    #pragma unroll
    for (int hl2 = 0; hl2 < 2; ++hl2) {
        int hl = wv * 2 + hl2;                  // 16 waves x 2 rows = 32 rows
        int h  = h0 + hl;                       // always < HOUT (h0 <= 2014)
        #pragma unroll
        for (int nh = 0; nh < 2; ++nh) {
            int wl = nh * 16;
            int tb = (hl * TC + wl) * 32;
            f32x4 acc = {0.f, 0.f, 0.f, 0.f};
            #pragma unroll
            for (int i = 0; i < 5; ++i) {
                bf16x8 a = *(const bf16x8*)(ldsb + (tb + off[i]));
                acc = __builtin_amdgcn_mfma_f32_16x16x32_bf16(a, wf[i], acc, 0, 0, 0);
            }
            // D: row = g*4+r = spatial, col = m = co  ->  float4 store
            int w = w0 + wl + g * 4;
            float* op = out + m * (size_t)PLANE_OUT + (size_t)h * WOUT + w;
            if (w + 3 < WOUT) {
                *(f32x4_u*)op = acc;
            } else {
                #pragma unroll
                for (int r = 0; r < 4; ++r)
                    if (w + r < WOUT) op[r] = acc[r];
            }
        }
    }
}

// ---------------- fallback (no workspace): fp32-staged single pass -----------
__global__ __launch_bounds__(256, 4)
void conv3x3_mfma(const float* __restrict__ x,
                  const float* __restrict__ k,
                  float* __restrict__ out) {
    __shared__ short lds2[TR * 34 * 16];
    const int tid  = threadIdx.x;
    const int lane = tid & 63;
    const int wv   = tid >> 6;
    const int m    = lane & 15;
    const int g    = lane >> 4;
    int bid = blockIdx.x;
    int swz = (bid & 7) * 512 + (bid >> 3);
    int h0 = (swz >> 6) * 32;
    int w0 = (swz & 63) * 32;
    for (int p = tid; p < TR * 34; p += 256) {
        int r = p / 34, c = p - r * 34;
        int hh = h0 + r; if (hh > HIN - 1) hh = HIN - 1;
        int ww = w0 + c; if (ww > WIN - 1) ww = WIN - 1;
        const float* gp = x + hh * WIN + ww;
        short t[16];
        #pragma unroll
        for (int ci = 0; ci < 16; ++ci) t[ci] = f2bf(gp[ci * PLANE_IN]);
        bf16x8 lo, hi;
        #pragma unroll
        for (int j = 0; j < 8; ++j) { lo[j] = t[j]; hi[j] = t[8 + j]; }
        int sw = (c >> 2) & 1;
        bf16x8* dst = (bf16x8*)&lds2[p * 16];
        dst[sw] = lo; dst[1 - sw] = hi;
    }
    bf16x8 wf[5];
    #pragma unroll
    for (int i = 0; i < 5; ++i)
        #pragma unroll
        for (int j = 0; j < 8; ++j) {
            int kk = 32 * i + 8 * g + j;
            int tap = kk >> 4, ci = kk & 15;
            short v = 0;
            if (tap < 9) v = f2bf(k[(m * 16 + ci) * 9 + tap]);
            wf[i][j] = v;
        }
    int off[5];
    #pragma unroll
    for (int i = 0; i < 5; ++i) {
        int tap = 2 * i + (g >> 1);
        if (tap > 8) tap = 8;
        int kh = tap / 3, kw = tap - kh * 3;
        int col = m + kw;
        int o = (kh * 34 + col) * 32 + (g & 1) * 16;
        off[i] = o ^ ((col & 4) << 2);
    }
    __syncthreads();
    const char* ldsb = (const char*)lds2;
    const int coBase = g * 4;
    for (int hl8 = 0; hl8 < 8; ++hl8) {
        int hl = wv * 8 + hl8;
        int h = h0 + hl;
        bool hok = (h < HOUT);
        #pragma unroll
        for (int nh = 0; nh < 2; ++nh) {
            int wl = nh * 16;
            int tb = (hl * 34 + wl) * 32;
            f32x4 acc = {0.f, 0.f, 0.f, 0.f};
            #pragma unroll
            for (int i = 0; i < 5; ++i) {
                bf16x8 b = *(const bf16x8*)(ldsb + (tb + off[i]));
                acc = __builtin_amdgcn_mfma_f32_16x16x32_bf16(wf[i], b, acc, 0, 0, 0);
            }
            int w = w0 + wl + m;
            if (hok && w < WOUT) {
                float* op = out + h * WOUT + w;
                #pragma unroll
                for (int r = 0; r < 4; ++r)
                    op[(coBase + r) * PLANE_OUT] = acc[r];
            }
        }
    }
}

extern "C" void kernel_launch(void* const* d_in, const int* in_sizes, int n_in,
                              void* d_out, int out_size, void* d_ws, size_t ws_size,
                              hipStream_t stream) {
    const float* x = (const float*)d_in[0];
    const float* k = (const float*)d_in[1];
    float* out = (float*)d_out;
    if (ws_size >= WF_U32 * 4) {
        unsigned* wfbuf = (unsigned*)d_ws;
        wf_setup<<<dim3(1), dim3(64), 0, stream>>>(k, wfbuf);
        conv3x3_fused1k<<<dim3(4096), dim3(1024), 0, stream>>>(x, wfbuf, out);
    } else {
        conv3x3_mfma<<<dim3(4096), dim3(256), 0, stream>>>(x, k, out);
    }
}